// Round 6
// baseline (35.559 us; speedup 1.0000x reference)
//
#include <hip/hip_runtime.h>
#include <stdint.h>

// R6: barrier-free per-wave pipeline.
//   Each WAVE (not WG) independently processes 4 batches (2916 words =
//   exactly 729 x 16B chunks):
//     1. 11-12 back-to-back global_load_lds 16B DMAs per lane (deep MLP)
//     2. s_waitcnt vmcnt(0)  -- waits only this wave's DMAs; NO barrier
//     3. lanes 0..35: one row each -- candidate masks, naked-pair logic,
//        write 1.0f/0.0f patterns back to the wave's LDS slot
//     4. coalesced dwordx4 LDS->global store (lgkmcnt orders vs step 3;
//        wave lockstep makes cross-lane LDS handoff safe without barriers)
//   Waves slip freely -> memory traffic stays continuous instead of
//   phase-aligned bursts (R5's residual cost).
//
// Row logic (validated R1-R5, absmax 0): cand[w] = 9-bit candidate mask of
// cell w; every pair-mask (popcount 2) occurring exactly twice in the row
// erases its digits from all cells whose cand differs from it.

#define WAVE_BATCHES 4
#define WAVE_WORDS (WAVE_BATCHES * 729)  // 2916 words = 11664 B
#define WAVE_CHUNKS (WAVE_WORDS / 4)     // 729 16B chunks
#define WAVES_PER_WG 4

typedef uint32_t u32x4 __attribute__((ext_vector_type(4)));
typedef const __attribute__((address_space(1))) uint32_t* gsrc_t;
typedef __attribute__((address_space(3))) uint32_t* lptr_t;

__global__ __launch_bounds__(256) void sudoku_kernel(
    const uint32_t* __restrict__ in, uint32_t* __restrict__ out, int nwaves) {
  __shared__ __align__(16) uint32_t lds[WAVES_PER_WG][WAVE_WORDS];
  const int lane = threadIdx.x & 63;
  const int wslot = threadIdx.x >> 6;
  const int wave_id = blockIdx.x * WAVES_PER_WG + wslot;
  if (wave_id >= nwaves) return;

  const uint32_t* gin = in + (size_t)wave_id * WAVE_WORDS;
  uint32_t* lbase = &lds[wslot][0];

  // ---- 1: global -> LDS, 16B DMA, coalesced, all issued back-to-back ----
#pragma unroll
  for (int j = 0; j < 12; ++j) {
    int i = lane + j * 64;
    if (i < WAVE_CHUNKS) {
      __builtin_amdgcn_global_load_lds((gsrc_t)(gin + i * 4),
                                       (lptr_t)(lbase + i * 4), 16, 0, 0);
    }
  }
  // ---- 2: wait own DMAs only (no workgroup barrier) ----
  asm volatile("s_waitcnt vmcnt(0)" ::: "memory");

  // ---- 3: per-row naked-pair logic, lanes 0..35 ----
  if (lane < WAVE_BATCHES * 9) {
    const int bl = lane / 9;
    const int h = lane - bl * 9;
    const int rbase = bl * 729 + h * 9;

    uint32_t cand[9];
#pragma unroll
    for (int w = 0; w < 9; ++w) cand[w] = 0u;
#pragma unroll
    for (int d = 0; d < 9; ++d) {
#pragma unroll
      for (int w = 0; w < 9; ++w)
        cand[w] |= (lbase[rbase + d * 81 + w] ? 1u : 0u) << d;
    }

    uint32_t clearbits[9];
#pragma unroll
    for (int w = 0; w < 9; ++w) clearbits[w] = 0u;
#pragma unroll
    for (int w1 = 0; w1 < 9; ++w1) {
      uint32_t c1 = cand[w1];
      if (__popc(c1) != 2) continue;
      int cnt = 0;
#pragma unroll
      for (int w2 = 0; w2 < 9; ++w2) cnt += (cand[w2] == c1) ? 1 : 0;
      if (cnt == 2) {
#pragma unroll
        for (int w = 0; w < 9; ++w)
          if (cand[w] != c1) clearbits[w] |= c1;
      }
    }

    uint32_t keep[9];
#pragma unroll
    for (int w = 0; w < 9; ++w) keep[w] = cand[w] & ~clearbits[w];

#pragma unroll
    for (int d = 0; d < 9; ++d) {
#pragma unroll
      for (int w = 0; w < 9; ++w)
        lbase[rbase + d * 81 + w] = ((keep[w] >> d) & 1u) ? 0x3F800000u : 0u;
    }
  }

  // ---- 4: LDS -> global, dwordx4, coalesced (lgkmcnt orders vs step 3;
  //         wave lockstep covers the cross-lane handoff) ----
  uint32_t* gout = out + (size_t)wave_id * WAVE_WORDS;
#pragma unroll
  for (int j = 0; j < 12; ++j) {
    int i = lane + j * 64;
    if (i < WAVE_CHUNKS) {
      u32x4 v = *(const u32x4*)(lbase + i * 4);
      *(u32x4*)(gout + i * 4) = v;
    }
  }
}

extern "C" void kernel_launch(void* const* d_in, const int* in_sizes, int n_in,
                              void* d_out, int out_size, void* d_ws, size_t ws_size,
                              hipStream_t stream) {
  const uint32_t* in = (const uint32_t*)d_in[0];  // mask, float32 binary
  uint32_t* out = (uint32_t*)d_out;               // float32 out, bit-patterns
  int B = in_sizes[0] / 729;
  int nwaves = (B + WAVE_BATCHES - 1) / WAVE_BATCHES;            // 8192
  int blocks = (nwaves + WAVES_PER_WG - 1) / WAVES_PER_WG;       // 2048
  sudoku_kernel<<<blocks, 256, 0, stream>>>(in, out, nwaves);
}